// Round 7
// baseline (532.534 us; speedup 1.0000x reference)
//
#include <hip/hip_runtime.h>
#include <math.h>

#define DEV static __device__ __forceinline__

typedef unsigned short u16;
typedef __attribute__((ext_vector_type(8))) short short8;
typedef __attribute__((ext_vector_type(4))) float floatx4;

// ---------- helpers ----------
DEV u16 f2bf(float f) {
  unsigned u = __float_as_uint(f);
  unsigned r = u + 0x7FFFu + ((u >> 16) & 1u);
  return (u16)(r >> 16);
}
DEV float bf2f(u16 v) { return __uint_as_float(((unsigned)v) << 16); }

typedef __attribute__((address_space(1))) void gvoid;
typedef __attribute__((address_space(3))) void lvoid;

DEV void gload16(const u16* g, u16* l) {
  // async global->LDS, 16B per lane; LDS dest = wave-uniform base + lane*16
  __builtin_amdgcn_global_load_lds((gvoid*)g, (lvoid*)l, 16, 0, 0);
}

// ---------- weight convert + transpose: out[n*K+k] = bf16(in[k*N+n]) ----------
__global__ __launch_bounds__(256) void tcast_k(const float* __restrict__ in,
                                               u16* __restrict__ out, int K, int N) {
  __shared__ float t[32][33];
  int nb = blockIdx.x * 32, kb = blockIdx.y * 32;
  int tx = threadIdx.x, ty = threadIdx.y;
#pragma unroll
  for (int r = 0; r < 32; r += 8)
    t[r + ty][tx] = in[(long)(kb + r + ty) * N + nb + tx];
  __syncthreads();
#pragma unroll
  for (int r = 0; r < 32; r += 8)
    out[(long)(nb + r + ty) * K + kb + tx] = f2bf(t[tx][r + ty]);
}

// ---------- layernorm: wave per row (D=512), bf16 out ----------
// TI = float (LN1, f32 input) or u16 (LN2, bf16 input)
template <typename TI>
__global__ __launch_bounds__(256) void ln_k(const TI* __restrict__ x,
                                            const float* __restrict__ g,
                                            const float* __restrict__ b,
                                            u16* __restrict__ xb) {
  const int lane = threadIdx.x & 63, wid = threadIdx.x >> 6;
  const long row = (long)blockIdx.x * 4 + wid;
  float vv[8];
  if constexpr (sizeof(TI) == 4) {
    const float4* xr = (const float4*)((const float*)x + row * 512);
    float4 v0 = xr[lane * 2], v1 = xr[lane * 2 + 1];
    vv[0] = v0.x; vv[1] = v0.y; vv[2] = v0.z; vv[3] = v0.w;
    vv[4] = v1.x; vv[5] = v1.y; vv[6] = v1.z; vv[7] = v1.w;
  } else {
    short8 v = *(const short8*)((const u16*)x + row * 512 + lane * 8);
#pragma unroll
    for (int i = 0; i < 8; ++i) vv[i] = bf2f((u16)v[i]);
  }
  float s = 0.f, q = 0.f;
#pragma unroll
  for (int i = 0; i < 8; ++i) { s += vv[i]; q += vv[i] * vv[i]; }
#pragma unroll
  for (int off = 1; off < 64; off <<= 1) {
    s += __shfl_xor(s, off, 64);
    q += __shfl_xor(q, off, 64);
  }
  float mean = s * (1.f / 512.f);
  float var = q * (1.f / 512.f) - mean * mean;
  float rs = rsqrtf(var + 1e-5f);
  const float4* gp = (const float4*)g;
  const float4* bp = (const float4*)b;
  float4 g0 = gp[lane * 2], g1 = gp[lane * 2 + 1];
  float4 b0 = bp[lane * 2], b1 = bp[lane * 2 + 1];
  float gg[8] = {g0.x, g0.y, g0.z, g0.w, g1.x, g1.y, g1.z, g1.w};
  float bb[8] = {b0.x, b0.y, b0.z, b0.w, b1.x, b1.y, b1.z, b1.w};
  short8 ov;
#pragma unroll
  for (int i = 0; i < 8; ++i)
    ov[i] = (short)f2bf((vv[i] - mean) * rs * gg[i] + bb[i]);
  *(short8*)&xb[row * 512 + lane * 8] = ov;
}

// ---------- GEMM: C[M,N] = A[M,K](bf16) * Bt[N,K]^T(bf16) + bias, epilogue ----------
// EPI 0: +bias -> bf16
// EPI 1: +bias, exact gelu -> bf16
// EPI 2: +bias, +res(bf16) -> bf16
// EPI 3: +bias, +res(bf16) -> f32
template <int EPI>
__global__ __launch_bounds__(256) void gemm_k(const u16* __restrict__ A,
                                              const u16* __restrict__ Bt,
                                              const float* __restrict__ bias,
                                              const u16* __restrict__ res,
                                              void* __restrict__ out,
                                              int M, int N, int K) {
  __shared__ __align__(16) u16 lA[128 * 32];
  __shared__ __align__(16) u16 lB[128 * 32];
  const int tid = threadIdx.x;
  const int lane = tid & 63, wid = tid >> 6;
  const int lane15 = lane & 15, khi = lane >> 4;
  const int wr = wid >> 1, wc = wid & 1;
  const long rowB = (long)blockIdx.y * 128;
  const long colB = (long)blockIdx.x * 128;

  floatx4 acc[4][4];
#pragma unroll
  for (int m = 0; m < 4; ++m)
#pragma unroll
    for (int n = 0; n < 4; ++n) acc[m][n] = floatx4{0.f, 0.f, 0.f, 0.f};

  for (int kt = 0; kt < K; kt += 32) {
    __syncthreads();
#pragma unroll
    for (int j = 0; j < 2; ++j) {
      int c = j * 256 + tid;
      int r = c >> 2, cq = c & 3;
      gload16(A + (rowB + r) * K + kt + cq * 8, &lA[(j * 256 + wid * 64) * 8]);
    }
#pragma unroll
    for (int j = 0; j < 2; ++j) {
      int c = j * 256 + tid;
      int r = c >> 2, cq = c & 3;
      gload16(Bt + (colB + r) * K + kt + cq * 8, &lB[(j * 256 + wid * 64) * 8]);
    }
    asm volatile("s_waitcnt vmcnt(0)" ::: "memory");
    __syncthreads();

    short8 af[4];
#pragma unroll
    for (int m = 0; m < 4; ++m)
      af[m] = *(const short8*)&lA[(wr * 64 + m * 16 + lane15) * 32 + khi * 8];
#pragma unroll
    for (int n = 0; n < 4; ++n) {
      short8 bfg = *(const short8*)&lB[(wc * 64 + n * 16 + lane15) * 32 + khi * 8];
#pragma unroll
      for (int m = 0; m < 4; ++m)
        acc[m][n] = __builtin_amdgcn_mfma_f32_16x16x32_bf16(af[m], bfg, acc[m][n], 0, 0, 0);
    }
  }

  const long r0 = rowB + wr * 64;
  const long c0 = colB + wc * 64;
#pragma unroll
  for (int m = 0; m < 4; ++m) {
#pragma unroll
    for (int n = 0; n < 4; ++n) {
      long col = c0 + n * 16 + lane15;
      float bv = bias[col];
#pragma unroll
      for (int jj = 0; jj < 4; ++jj) {
        long row = r0 + m * 16 + khi * 4 + jj;
        float v = acc[m][n][jj] + bv;
        if (EPI == 1) v = 0.5f * v * (1.f + erff(v * 0.70710678118f));
        if (EPI == 2 || EPI == 3) v += bf2f(res[row * N + col]);
        if (EPI == 3) {
          ((float*)out)[row * N + col] = v;
        } else {
          ((u16*)out)[row * N + col] = f2bf(v);
        }
      }
    }
  }
}

// ---------- fused causal attention, one workgroup per (b,a,h) ----------
// qkv: [32768, 1536] bf16 (q|k|v each 512 cols, head h at h*64). y: [32768,512] bf16
__global__ __launch_bounds__(256) void attn_k(const u16* __restrict__ qkv,
                                              u16* __restrict__ y) {
  union U {
    struct { u16 q[128 * 64]; u16 k[128 * 64]; } qk;
    u16 p[128 * 128];
  };
  __shared__ __align__(16) U u;
  __shared__ __align__(16) u16 vt[64 * 128];

  const int tid = threadIdx.x;
  const int lane = tid & 63, wid = tid >> 6;
  const int lane15 = lane & 15, khi = lane >> 4;
  const int h = blockIdx.x & 7;
  const long R0 = (long)(blockIdx.x >> 3) * 128;
  const u16* base = qkv + R0 * 1536 + h * 64;

  // stage Q,K (row-major swizzled), V transposed (swizzled)
#pragma unroll
  for (int it = 0; it < 4; ++it) {
    int c = it * 256 + tid;      // 1024 chunks of 8 bf16
    int r = c >> 3, ch = c & 7;
    const u16* gq = base + (long)r * 1536 + ch * 8;
    uint4 dq = *(const uint4*)gq;
    uint4 dk = *(const uint4*)(gq + 512);
    uint4 dv = *(const uint4*)(gq + 1024);
    int qi = (r * 64 + ch * 8) ^ ((r & 7) << 3);
    *(uint4*)&u.qk.q[qi] = dq;
    *(uint4*)&u.qk.k[qi] = dk;
    u16 tmp[8];
    *(uint4*)tmp = dv;
#pragma unroll
    for (int i = 0; i < 8; ++i) {
      int d = ch * 8 + i;
      vt[(d * 128 + r) ^ ((d & 7) << 3)] = tmp[i];
    }
  }
  __syncthreads();

  // QK^T: wave owns rows [wid*32, wid*32+32)
  const int r0 = wid * 32;
  floatx4 sc[2][8];
#pragma unroll
  for (int mt = 0; mt < 2; ++mt)
#pragma unroll
    for (int c = 0; c < 8; ++c) sc[mt][c] = floatx4{0.f, 0.f, 0.f, 0.f};

#pragma unroll
  for (int kk = 0; kk < 2; ++kk) {
    short8 aq[2];
#pragma unroll
    for (int mt = 0; mt < 2; ++mt) {
      int rr = r0 + mt * 16 + lane15;
      aq[mt] = *(const short8*)&u.qk.q[(rr * 64 + kk * 32 + khi * 8) ^ ((rr & 7) << 3)];
    }
#pragma unroll
    for (int c = 0; c < 8; ++c) {
      int rk = c * 16 + lane15;
      short8 bk = *(const short8*)&u.qk.k[(rk * 64 + kk * 32 + khi * 8) ^ ((rk & 7) << 3)];
#pragma unroll
      for (int mt = 0; mt < 2; ++mt)
        sc[mt][c] = __builtin_amdgcn_mfma_f32_16x16x32_bf16(aq[mt], bk, sc[mt][c], 0, 0, 0);
    }
  }
  __syncthreads();  // all waves done reading Q/K before P overwrites them

  // softmax (fp32, full row materialized) + write P (bf16, swizzled)
#pragma unroll
  for (int mt = 0; mt < 2; ++mt) {
#pragma unroll
    for (int jj = 0; jj < 4; ++jj) {
      int t = r0 + mt * 16 + khi * 4 + jj;
      float vals[8];
      float mx = -1e30f;
#pragma unroll
      for (int c = 0; c < 8; ++c) {
        int s = c * 16 + lane15;
        float v = sc[mt][c][jj] * 0.125f;
        vals[c] = (s <= t) ? v : -1e30f;
        mx = fmaxf(mx, vals[c]);
      }
#pragma unroll
      for (int off = 1; off < 16; off <<= 1) mx = fmaxf(mx, __shfl_xor(mx, off, 64));
      float sum = 0.f;
#pragma unroll
      for (int c = 0; c < 8; ++c) {
        float p = __expf(vals[c] - mx);  // masked -> exp(-huge) = 0
        vals[c] = p;
        sum += p;
      }
#pragma unroll
      for (int off = 1; off < 16; off <<= 1) sum += __shfl_xor(sum, off, 64);
      float inv = 1.f / sum;
#pragma unroll
      for (int c = 0; c < 8; ++c) {
        int s = c * 16 + lane15;
        u.p[(t * 128 + s) ^ ((t & 7) << 3)] = f2bf(vals[c] * inv);
      }
    }
  }
  __syncthreads();

  // PV: Y[r0..r0+32][0..64]
  floatx4 ya[2][4];
#pragma unroll
  for (int mt = 0; mt < 2; ++mt)
#pragma unroll
    for (int n = 0; n < 4; ++n) ya[mt][n] = floatx4{0.f, 0.f, 0.f, 0.f};

#pragma unroll
  for (int kk = 0; kk < 4; ++kk) {
    short8 ap[2];
#pragma unroll
    for (int mt = 0; mt < 2; ++mt) {
      int rr = r0 + mt * 16 + lane15;
      ap[mt] = *(const short8*)&u.p[(rr * 128 + kk * 32 + khi * 8) ^ ((rr & 7) << 3)];
    }
#pragma unroll
    for (int n = 0; n < 4; ++n) {
      int d = n * 16 + lane15;
      short8 bv = *(const short8*)&vt[(d * 128 + kk * 32 + khi * 8) ^ ((d & 7) << 3)];
#pragma unroll
      for (int mt = 0; mt < 2; ++mt)
        ya[mt][n] = __builtin_amdgcn_mfma_f32_16x16x32_bf16(ap[mt], bv, ya[mt][n], 0, 0, 0);
    }
  }

  u16* yb = y + R0 * 512 + h * 64;
#pragma unroll
  for (int mt = 0; mt < 2; ++mt)
#pragma unroll
    for (int n = 0; n < 4; ++n)
#pragma unroll
      for (int jj = 0; jj < 4; ++jj) {
        int t = r0 + mt * 16 + khi * 4 + jj;
        int d = n * 16 + lane15;
        yb[(long)t * 512 + d] = f2bf(ya[mt][n][jj]);
      }
}

// ---------- launch ----------
// ws layout (liveness-packed, peak 168 MiB):
//   [0,6M)      bf16 weights wq|wp|wf|wo (live whole launch)
//   [8M,40M)    xnB   (LN1 -> proj residual), then xn2B (LN2 -> out residual)
//   [40M,136M)  qkvB  (QKV -> attn), then x2B at [40M,72M) (proj -> LN2)
//   [136M,168M) yB    (attn -> proj)
//   [40M,168M)  hB    (fc -> out)   — overlays qkvB/x2B/yB, all dead by then
extern "C" void kernel_launch(void* const* d_in, const int* in_sizes, int n_in,
                              void* d_out, int out_size, void* d_ws, size_t ws_size,
                              hipStream_t stream) {
  const float* x      = (const float*)d_in[0];
  const float* ln1_g  = (const float*)d_in[1];
  const float* ln1_b  = (const float*)d_in[2];
  const float* W_qkv  = (const float*)d_in[3];
  const float* b_qkv  = (const float*)d_in[4];
  const float* W_proj = (const float*)d_in[5];
  const float* b_proj = (const float*)d_in[6];
  const float* ln2_g  = (const float*)d_in[7];
  const float* ln2_b  = (const float*)d_in[8];
  const float* W_fc   = (const float*)d_in[9];
  const float* b_fc   = (const float*)d_in[10];
  const float* W_out  = (const float*)d_in[11];
  const float* b_out  = (const float*)d_in[12];

  const size_t MiB = 1024 * 1024;
  char* ws = (char*)d_ws;
  u16* wq   = (u16*)(ws + 0);                        // [1536,512]  1.5 MiB
  u16* wp   = (u16*)(ws + 1536 * 512 * 2);           // [512,512]   0.5 MiB
  u16* wf   = (u16*)(ws + 2 * MiB);                  // [2048,512]  2 MiB
  u16* wo   = (u16*)(ws + 4 * MiB);                  // [512,2048]  2 MiB
  u16* xnB  = (u16*)(ws + 8 * MiB);                  // 32 MiB
  u16* qkvB = (u16*)(ws + 40 * MiB);                 // 96 MiB
  u16* yB   = (u16*)(ws + 136 * MiB);                // 32 MiB
  u16* x2B  = (u16*)(ws + 40 * MiB);                 // 32 MiB (reuse qkvB)
  u16* xn2B = (u16*)(ws + 8 * MiB);                  // 32 MiB (reuse xnB)
  u16* hB   = (u16*)(ws + 40 * MiB);                 // 128 MiB (reuse qkv/x2/y)

  const int M = 32768;

  // weights -> bf16 transposed (B^T layout for contiguous-K fragment reads)
  tcast_k<<<dim3(1536 / 32, 512 / 32), dim3(32, 8), 0, stream>>>(W_qkv, wq, 512, 1536);
  tcast_k<<<dim3(512 / 32, 512 / 32), dim3(32, 8), 0, stream>>>(W_proj, wp, 512, 512);
  tcast_k<<<dim3(2048 / 32, 512 / 32), dim3(32, 8), 0, stream>>>(W_fc, wf, 512, 2048);
  tcast_k<<<dim3(512 / 32, 2048 / 32), dim3(32, 8), 0, stream>>>(W_out, wo, 2048, 512);

  // LN1
  ln_k<float><<<M / 4, 256, 0, stream>>>(x, ln1_g, ln1_b, xnB);
  // QKV
  gemm_k<0><<<dim3(1536 / 128, M / 128), 256, 0, stream>>>(xnB, wq, b_qkv, nullptr,
                                                           qkvB, M, 1536, 512);
  // attention
  attn_k<<<2048, 256, 0, stream>>>(qkvB, yB);
  // proj + residual(xn) -> x2 (bf16)
  gemm_k<2><<<dim3(512 / 128, M / 128), 256, 0, stream>>>(yB, wp, b_proj, xnB,
                                                          x2B, M, 512, 512);
  // LN2
  ln_k<u16><<<M / 4, 256, 0, stream>>>(x2B, ln2_g, ln2_b, xn2B);
  // FC + gelu
  gemm_k<1><<<dim3(2048 / 128, M / 128), 256, 0, stream>>>(xn2B, wf, b_fc, nullptr,
                                                           hB, M, 2048, 512);
  // OUT + residual(xn2) -> d_out (f32)
  gemm_k<3><<<dim3(512 / 128, M / 128), 256, 0, stream>>>(hB, wo, b_out, xn2B,
                                                          (float*)d_out, M, 512, 2048);
}

// Round 8
// 507.698 us; speedup vs baseline: 1.0489x; 1.0489x over previous
//
#include <hip/hip_runtime.h>
#include <math.h>

#define DEV static __device__ __forceinline__

typedef unsigned short u16;
typedef __attribute__((ext_vector_type(8))) short short8;
typedef __attribute__((ext_vector_type(4))) float floatx4;

// ---------- helpers ----------
DEV u16 f2bf(float f) {
  unsigned u = __float_as_uint(f);
  unsigned r = u + 0x7FFFu + ((u >> 16) & 1u);
  return (u16)(r >> 16);
}
DEV float bf2f(u16 v) { return __uint_as_float(((unsigned)v) << 16); }

typedef __attribute__((address_space(1))) void gvoid;
typedef __attribute__((address_space(3))) void lvoid;

DEV void gload16(const u16* g, u16* l) {
  // async global->LDS, 16B per lane; LDS dest = wave-uniform base + lane*16
  __builtin_amdgcn_global_load_lds((gvoid*)g, (lvoid*)l, 16, 0, 0);
}

// ---------- weight convert + transpose: out[n*K+k] = bf16(in[k*N+n]) ----------
__global__ __launch_bounds__(256) void tcast_k(const float* __restrict__ in,
                                               u16* __restrict__ out, int K, int N) {
  __shared__ float t[32][33];
  int nb = blockIdx.x * 32, kb = blockIdx.y * 32;
  int tx = threadIdx.x, ty = threadIdx.y;
#pragma unroll
  for (int r = 0; r < 32; r += 8)
    t[r + ty][tx] = in[(long)(kb + r + ty) * N + nb + tx];
  __syncthreads();
#pragma unroll
  for (int r = 0; r < 32; r += 8)
    out[(long)(nb + r + ty) * K + kb + tx] = f2bf(t[tx][r + ty]);
}

// ---------- layernorm: wave per row (D=512), bf16 out ----------
// TI = float (LN1, f32 input) or u16 (LN2, bf16 input)
template <typename TI>
__global__ __launch_bounds__(256) void ln_k(const TI* __restrict__ x,
                                            const float* __restrict__ g,
                                            const float* __restrict__ b,
                                            u16* __restrict__ xb) {
  const int lane = threadIdx.x & 63, wid = threadIdx.x >> 6;
  const long row = (long)blockIdx.x * 4 + wid;
  float vv[8];
  if constexpr (sizeof(TI) == 4) {
    const float4* xr = (const float4*)((const float*)x + row * 512);
    float4 v0 = xr[lane * 2], v1 = xr[lane * 2 + 1];
    vv[0] = v0.x; vv[1] = v0.y; vv[2] = v0.z; vv[3] = v0.w;
    vv[4] = v1.x; vv[5] = v1.y; vv[6] = v1.z; vv[7] = v1.w;
  } else {
    short8 v = *(const short8*)((const u16*)x + row * 512 + lane * 8);
#pragma unroll
    for (int i = 0; i < 8; ++i) vv[i] = bf2f((u16)v[i]);
  }
  float s = 0.f, q = 0.f;
#pragma unroll
  for (int i = 0; i < 8; ++i) { s += vv[i]; q += vv[i] * vv[i]; }
#pragma unroll
  for (int off = 1; off < 64; off <<= 1) {
    s += __shfl_xor(s, off, 64);
    q += __shfl_xor(q, off, 64);
  }
  float mean = s * (1.f / 512.f);
  float var = q * (1.f / 512.f) - mean * mean;
  float rs = rsqrtf(var + 1e-5f);
  const float4* gp = (const float4*)g;
  const float4* bp = (const float4*)b;
  float4 g0 = gp[lane * 2], g1 = gp[lane * 2 + 1];
  float4 b0 = bp[lane * 2], b1 = bp[lane * 2 + 1];
  float gg[8] = {g0.x, g0.y, g0.z, g0.w, g1.x, g1.y, g1.z, g1.w};
  float bb[8] = {b0.x, b0.y, b0.z, b0.w, b1.x, b1.y, b1.z, b1.w};
  short8 ov;
#pragma unroll
  for (int i = 0; i < 8; ++i)
    ov[i] = (short)f2bf((vv[i] - mean) * rs * gg[i] + bb[i]);
  *(short8*)&xb[row * 512 + lane * 8] = ov;
}

// ---------- GEMM: C[M,N] = A[M,K](bf16) * Bt[N,K]^T(bf16) + bias, epilogue ----------
// 2-phase double-buffered K-loop (prefetch next tile before compute), XCD-chunked
// block swizzle for A-panel L2 locality.
// EPI 0: +bias -> bf16
// EPI 1: +bias, exact gelu -> bf16
// EPI 2: +bias, +res(bf16) -> bf16
// EPI 3: +bias, +res(bf16) -> f32
template <int EPI>
__global__ __launch_bounds__(256) void gemm_k(const u16* __restrict__ A,
                                              const u16* __restrict__ Bt,
                                              const float* __restrict__ bias,
                                              const u16* __restrict__ res,
                                              void* __restrict__ out,
                                              int M, int N, int K) {
  __shared__ __align__(16) u16 lA[2][128 * 32];
  __shared__ __align__(16) u16 lB[2][128 * 32];
  const int tid = threadIdx.x;
  const int lane = tid & 63, wid = tid >> 6;
  const int lane15 = lane & 15, khi = lane >> 4;
  const int wr = wid >> 1, wc = wid & 1;

  // XCD-aware chunked swizzle (bijective: nwg % 8 == 0 for all our grids).
  // Consecutive-dispatch blocks land on the same XCD in contiguous logical
  // chunks -> tile-rows (which share the A panel) stay in one L2.
  const int gx = gridDim.x;
  const int nwg = gx * gridDim.y;
  const int orig = blockIdx.y * gx + blockIdx.x;
  const int wgid = (orig & 7) * (nwg >> 3) + (orig >> 3);
  const int bx = wgid % gx;
  const int by = wgid / gx;

  const long rowB = (long)by * 128;
  const long colB = (long)bx * 128;

  // per-lane staging source pointers (16B per lane per gload)
  const int rr = tid >> 2, cq = tid & 3;
  const u16* gA0 = A + (rowB + rr) * (long)K + cq * 8;
  const u16* gB0 = Bt + (colB + rr) * (long)K + cq * 8;
  const long skip = 64 * (long)K;

  floatx4 acc[4][4];
#pragma unroll
  for (int m = 0; m < 4; ++m)
#pragma unroll
    for (int n = 0; n < 4; ++n) acc[m][n] = floatx4{0.f, 0.f, 0.f, 0.f};

  auto stage = [&](int buf, int kt) {
    gload16(gA0 + kt, &lA[buf][(wid * 64) * 8]);
    gload16(gA0 + skip + kt, &lA[buf][(256 + wid * 64) * 8]);
    gload16(gB0 + kt, &lB[buf][(wid * 64) * 8]);
    gload16(gB0 + skip + kt, &lB[buf][(256 + wid * 64) * 8]);
  };

  // prologue: fill buffer 0
  stage(0, 0);
  asm volatile("s_waitcnt vmcnt(0)" ::: "memory");
  __syncthreads();

  const int nt = K >> 5;
  for (int t = 0; t < nt; ++t) {
    const int cur = t & 1;
    if (t + 1 < nt) stage(cur ^ 1, (t + 1) << 5);  // prefetch next tile (issue early)
    __builtin_amdgcn_sched_barrier(0);             // keep issue before compute
    short8 af[4];
#pragma unroll
    for (int m = 0; m < 4; ++m)
      af[m] = *(const short8*)&lA[cur][(wr * 64 + m * 16 + lane15) * 32 + khi * 8];
#pragma unroll
    for (int n = 0; n < 4; ++n) {
      short8 bfg = *(const short8*)&lB[cur][(wc * 64 + n * 16 + lane15) * 32 + khi * 8];
#pragma unroll
      for (int m = 0; m < 4; ++m)
        acc[m][n] = __builtin_amdgcn_mfma_f32_16x16x32_bf16(af[m], bfg, acc[m][n], 0, 0, 0);
    }
    asm volatile("s_waitcnt vmcnt(0)" ::: "memory");
    __syncthreads();
  }

  const long r0 = rowB + wr * 64;
  const long c0 = colB + wc * 64;
#pragma unroll
  for (int m = 0; m < 4; ++m) {
#pragma unroll
    for (int n = 0; n < 4; ++n) {
      long col = c0 + n * 16 + lane15;
      float bv = bias[col];
#pragma unroll
      for (int jj = 0; jj < 4; ++jj) {
        long row = r0 + m * 16 + khi * 4 + jj;
        float v = acc[m][n][jj] + bv;
        if (EPI == 1) v = 0.5f * v * (1.f + erff(v * 0.70710678118f));
        if (EPI == 2 || EPI == 3) v += bf2f(res[row * N + col]);
        if (EPI == 3) {
          ((float*)out)[row * N + col] = v;
        } else {
          ((u16*)out)[row * N + col] = f2bf(v);
        }
      }
    }
  }
}

// ---------- fused causal attention, one workgroup per (b,a,h) ----------
// qkv: [32768, 1536] bf16 (q|k|v each 512 cols, head h at h*64). y: [32768,512] bf16
__global__ __launch_bounds__(256) void attn_k(const u16* __restrict__ qkv,
                                              u16* __restrict__ y) {
  union U {
    struct { u16 q[128 * 64]; u16 k[128 * 64]; } qk;
    u16 p[128 * 128];
  };
  __shared__ __align__(16) U u;
  __shared__ __align__(16) u16 vt[64 * 128];

  const int tid = threadIdx.x;
  const int lane = tid & 63, wid = tid >> 6;
  const int lane15 = lane & 15, khi = lane >> 4;
  const int h = blockIdx.x & 7;
  const long R0 = (long)(blockIdx.x >> 3) * 128;
  const u16* base = qkv + R0 * 1536 + h * 64;

  // stage Q,K (row-major swizzled), V transposed (swizzled)
#pragma unroll
  for (int it = 0; it < 4; ++it) {
    int c = it * 256 + tid;      // 1024 chunks of 8 bf16
    int r = c >> 3, ch = c & 7;
    const u16* gq = base + (long)r * 1536 + ch * 8;
    uint4 dq = *(const uint4*)gq;
    uint4 dk = *(const uint4*)(gq + 512);
    uint4 dv = *(const uint4*)(gq + 1024);
    int qi = (r * 64 + ch * 8) ^ ((r & 7) << 3);
    *(uint4*)&u.qk.q[qi] = dq;
    *(uint4*)&u.qk.k[qi] = dk;
    u16 tmp[8];
    *(uint4*)tmp = dv;
#pragma unroll
    for (int i = 0; i < 8; ++i) {
      int d = ch * 8 + i;
      vt[(d * 128 + r) ^ ((d & 7) << 3)] = tmp[i];
    }
  }
  __syncthreads();

  // QK^T: wave owns rows [wid*32, wid*32+32)
  const int r0 = wid * 32;
  floatx4 sc[2][8];
#pragma unroll
  for (int mt = 0; mt < 2; ++mt)
#pragma unroll
    for (int c = 0; c < 8; ++c) sc[mt][c] = floatx4{0.f, 0.f, 0.f, 0.f};

#pragma unroll
  for (int kk = 0; kk < 2; ++kk) {
    short8 aq[2];
#pragma unroll
    for (int mt = 0; mt < 2; ++mt) {
      int rr = r0 + mt * 16 + lane15;
      aq[mt] = *(const short8*)&u.qk.q[(rr * 64 + kk * 32 + khi * 8) ^ ((rr & 7) << 3)];
    }
#pragma unroll
    for (int c = 0; c < 8; ++c) {
      int rk = c * 16 + lane15;
      short8 bk = *(const short8*)&u.qk.k[(rk * 64 + kk * 32 + khi * 8) ^ ((rk & 7) << 3)];
#pragma unroll
      for (int mt = 0; mt < 2; ++mt)
        sc[mt][c] = __builtin_amdgcn_mfma_f32_16x16x32_bf16(aq[mt], bk, sc[mt][c], 0, 0, 0);
    }
  }
  __syncthreads();  // all waves done reading Q/K before P overwrites them

  // softmax (fp32, full row materialized) + write P (bf16, swizzled)
#pragma unroll
  for (int mt = 0; mt < 2; ++mt) {
#pragma unroll
    for (int jj = 0; jj < 4; ++jj) {
      int t = r0 + mt * 16 + khi * 4 + jj;
      float vals[8];
      float mx = -1e30f;
#pragma unroll
      for (int c = 0; c < 8; ++c) {
        int s = c * 16 + lane15;
        float v = sc[mt][c][jj] * 0.125f;
        vals[c] = (s <= t) ? v : -1e30f;
        mx = fmaxf(mx, vals[c]);
      }
#pragma unroll
      for (int off = 1; off < 16; off <<= 1) mx = fmaxf(mx, __shfl_xor(mx, off, 64));
      float sum = 0.f;
#pragma unroll
      for (int c = 0; c < 8; ++c) {
        float p = __expf(vals[c] - mx);  // masked -> exp(-huge) = 0
        vals[c] = p;
        sum += p;
      }
#pragma unroll
      for (int off = 1; off < 16; off <<= 1) sum += __shfl_xor(sum, off, 64);
      float inv = 1.f / sum;
#pragma unroll
      for (int c = 0; c < 8; ++c) {
        int s = c * 16 + lane15;
        u.p[(t * 128 + s) ^ ((t & 7) << 3)] = f2bf(vals[c] * inv);
      }
    }
  }
  __syncthreads();

  // PV: Y[r0..r0+32][0..64]
  floatx4 ya[2][4];
#pragma unroll
  for (int mt = 0; mt < 2; ++mt)
#pragma unroll
    for (int n = 0; n < 4; ++n) ya[mt][n] = floatx4{0.f, 0.f, 0.f, 0.f};

#pragma unroll
  for (int kk = 0; kk < 4; ++kk) {
    short8 ap[2];
#pragma unroll
    for (int mt = 0; mt < 2; ++mt) {
      int rr = r0 + mt * 16 + lane15;
      ap[mt] = *(const short8*)&u.p[(rr * 128 + kk * 32 + khi * 8) ^ ((rr & 7) << 3)];
    }
#pragma unroll
    for (int n = 0; n < 4; ++n) {
      int d = n * 16 + lane15;
      short8 bv = *(const short8*)&vt[(d * 128 + kk * 32 + khi * 8) ^ ((d & 7) << 3)];
#pragma unroll
      for (int mt = 0; mt < 2; ++mt)
        ya[mt][n] = __builtin_amdgcn_mfma_f32_16x16x32_bf16(ap[mt], bv, ya[mt][n], 0, 0, 0);
    }
  }

  u16* yb = y + R0 * 512 + h * 64;
#pragma unroll
  for (int mt = 0; mt < 2; ++mt)
#pragma unroll
    for (int n = 0; n < 4; ++n)
#pragma unroll
      for (int jj = 0; jj < 4; ++jj) {
        int t = r0 + mt * 16 + khi * 4 + jj;
        int d = n * 16 + lane15;
        yb[(long)t * 512 + d] = f2bf(ya[mt][n][jj]);
      }
}

// ---------- launch ----------
// ws layout (liveness-packed, peak 168 MiB):
//   [0,6M)      bf16 weights wq|wp|wf|wo (live whole launch)
//   [8M,40M)    xnB   (LN1 -> proj residual), then xn2B (LN2 -> out residual)
//   [40M,136M)  qkvB  (QKV -> attn), then x2B at [40M,72M) (proj -> LN2)
//   [136M,168M) yB    (attn -> proj)
//   [40M,168M)  hB    (fc -> out)   — overlays qkvB/x2B/yB, all dead by then
extern "C" void kernel_launch(void* const* d_in, const int* in_sizes, int n_in,
                              void* d_out, int out_size, void* d_ws, size_t ws_size,
                              hipStream_t stream) {
  const float* x      = (const float*)d_in[0];
  const float* ln1_g  = (const float*)d_in[1];
  const float* ln1_b  = (const float*)d_in[2];
  const float* W_qkv  = (const float*)d_in[3];
  const float* b_qkv  = (const float*)d_in[4];
  const float* W_proj = (const float*)d_in[5];
  const float* b_proj = (const float*)d_in[6];
  const float* ln2_g  = (const float*)d_in[7];
  const float* ln2_b  = (const float*)d_in[8];
  const float* W_fc   = (const float*)d_in[9];
  const float* b_fc   = (const float*)d_in[10];
  const float* W_out  = (const float*)d_in[11];
  const float* b_out  = (const float*)d_in[12];

  const size_t MiB = 1024 * 1024;
  char* ws = (char*)d_ws;
  u16* wq   = (u16*)(ws + 0);                        // [1536,512]  1.5 MiB
  u16* wp   = (u16*)(ws + 1536 * 512 * 2);           // [512,512]   0.5 MiB
  u16* wf   = (u16*)(ws + 2 * MiB);                  // [2048,512]  2 MiB
  u16* wo   = (u16*)(ws + 4 * MiB);                  // [512,2048]  2 MiB
  u16* xnB  = (u16*)(ws + 8 * MiB);                  // 32 MiB
  u16* qkvB = (u16*)(ws + 40 * MiB);                 // 96 MiB
  u16* yB   = (u16*)(ws + 136 * MiB);                // 32 MiB
  u16* x2B  = (u16*)(ws + 40 * MiB);                 // 32 MiB (reuse qkvB)
  u16* xn2B = (u16*)(ws + 8 * MiB);                  // 32 MiB (reuse xnB)
  u16* hB   = (u16*)(ws + 40 * MiB);                 // 128 MiB (reuse qkv/x2/y)

  const int M = 32768;

  // weights -> bf16 transposed (B^T layout for contiguous-K fragment reads)
  tcast_k<<<dim3(1536 / 32, 512 / 32), dim3(32, 8), 0, stream>>>(W_qkv, wq, 512, 1536);
  tcast_k<<<dim3(512 / 32, 512 / 32), dim3(32, 8), 0, stream>>>(W_proj, wp, 512, 512);
  tcast_k<<<dim3(2048 / 32, 512 / 32), dim3(32, 8), 0, stream>>>(W_fc, wf, 512, 2048);
  tcast_k<<<dim3(512 / 32, 2048 / 32), dim3(32, 8), 0, stream>>>(W_out, wo, 2048, 512);

  // LN1
  ln_k<float><<<M / 4, 256, 0, stream>>>(x, ln1_g, ln1_b, xnB);
  // QKV
  gemm_k<0><<<dim3(1536 / 128, M / 128), 256, 0, stream>>>(xnB, wq, b_qkv, nullptr,
                                                           qkvB, M, 1536, 512);
  // attention
  attn_k<<<2048, 256, 0, stream>>>(qkvB, yB);
  // proj + residual(xn) -> x2 (bf16)
  gemm_k<2><<<dim3(512 / 128, M / 128), 256, 0, stream>>>(yB, wp, b_proj, xnB,
                                                          x2B, M, 512, 512);
  // LN2
  ln_k<u16><<<M / 4, 256, 0, stream>>>(x2B, ln2_g, ln2_b, xn2B);
  // FC + gelu
  gemm_k<1><<<dim3(2048 / 128, M / 128), 256, 0, stream>>>(xn2B, wf, b_fc, nullptr,
                                                           hB, M, 2048, 512);
  // OUT + residual(xn2) -> d_out (f32)
  gemm_k<3><<<dim3(512 / 128, M / 128), 256, 0, stream>>>(hB, wo, b_out, xn2B,
                                                          (float*)d_out, M, 512, 2048);
}

// Round 10
// 475.679 us; speedup vs baseline: 1.1195x; 1.0673x over previous
//
#include <hip/hip_runtime.h>
#include <math.h>

#define DEV static __device__ __forceinline__

typedef unsigned short u16;
typedef __attribute__((ext_vector_type(8))) short short8;
typedef __attribute__((ext_vector_type(4))) float floatx4;

// ---------- helpers ----------
DEV u16 f2bf(float f) {
  unsigned u = __float_as_uint(f);
  unsigned r = u + 0x7FFFu + ((u >> 16) & 1u);
  return (u16)(r >> 16);
}
DEV float bf2f(u16 v) { return __uint_as_float(((unsigned)v) << 16); }

typedef __attribute__((address_space(1))) void gvoid;
typedef __attribute__((address_space(3))) void lvoid;

DEV void gload16(const u16* g, u16* l) {
  // async global->LDS, 16B per lane; LDS dest = wave-uniform base + lane*16
  __builtin_amdgcn_global_load_lds((gvoid*)g, (lvoid*)l, 16, 0, 0);
}

// ---------- weight convert + transpose: out[n*K+k] = bf16(in[k*N+n]) ----------
__global__ __launch_bounds__(256) void tcast_k(const float* __restrict__ in,
                                               u16* __restrict__ out, int K, int N) {
  __shared__ float t[32][33];
  int nb = blockIdx.x * 32, kb = blockIdx.y * 32;
  int tx = threadIdx.x, ty = threadIdx.y;
#pragma unroll
  for (int r = 0; r < 32; r += 8)
    t[r + ty][tx] = in[(long)(kb + r + ty) * N + nb + tx];
  __syncthreads();
#pragma unroll
  for (int r = 0; r < 32; r += 8)
    out[(long)(nb + r + ty) * K + kb + tx] = f2bf(t[tx][r + ty]);
}

// ---------- layernorm: wave per row (D=512), bf16 out ----------
template <typename TI>
__global__ __launch_bounds__(256) void ln_k(const TI* __restrict__ x,
                                            const float* __restrict__ g,
                                            const float* __restrict__ b,
                                            u16* __restrict__ xb) {
  const int lane = threadIdx.x & 63, wid = threadIdx.x >> 6;
  const long row = (long)blockIdx.x * 4 + wid;
  float vv[8];
  if constexpr (sizeof(TI) == 4) {
    const float4* xr = (const float4*)((const float*)x + row * 512);
    float4 v0 = xr[lane * 2], v1 = xr[lane * 2 + 1];
    vv[0] = v0.x; vv[1] = v0.y; vv[2] = v0.z; vv[3] = v0.w;
    vv[4] = v1.x; vv[5] = v1.y; vv[6] = v1.z; vv[7] = v1.w;
  } else {
    short8 v = *(const short8*)((const u16*)x + row * 512 + lane * 8);
#pragma unroll
    for (int i = 0; i < 8; ++i) vv[i] = bf2f((u16)v[i]);
  }
  float s = 0.f, q = 0.f;
#pragma unroll
  for (int i = 0; i < 8; ++i) { s += vv[i]; q += vv[i] * vv[i]; }
#pragma unroll
  for (int off = 1; off < 64; off <<= 1) {
    s += __shfl_xor(s, off, 64);
    q += __shfl_xor(q, off, 64);
  }
  float mean = s * (1.f / 512.f);
  float var = q * (1.f / 512.f) - mean * mean;
  float rs = rsqrtf(var + 1e-5f);
  const float4* gp = (const float4*)g;
  const float4* bp = (const float4*)b;
  float4 g0 = gp[lane * 2], g1 = gp[lane * 2 + 1];
  float4 b0 = bp[lane * 2], b1 = bp[lane * 2 + 1];
  float gg[8] = {g0.x, g0.y, g0.z, g0.w, g1.x, g1.y, g1.z, g1.w};
  float bb[8] = {b0.x, b0.y, b0.z, b0.w, b1.x, b1.y, b1.z, b1.w};
  short8 ov;
#pragma unroll
  for (int i = 0; i < 8; ++i)
    ov[i] = (short)f2bf((vv[i] - mean) * rs * gg[i] + bb[i]);
  *(short8*)&xb[row * 512 + lane * 8] = ov;
}

// ---------- GEMM 256x256, 8 waves, BK=32, 4-buffer counted-vmcnt pipeline ----------
// C[M,N] = A[M,K](bf16) * Bt[N,K]^T(bf16) + bias, epilogue as before.
// LDS read swizzle sw(r)=(((r>>1)&3)<<4) on byte col; global source pre-swizzled
// so linear global_load_lds dest + swizzled ds_read agree (rule 21).
template <int EPI>
__global__ __launch_bounds__(512) void gemm_k(const u16* __restrict__ A,
                                              const u16* __restrict__ Bt,
                                              const float* __restrict__ bias,
                                              const u16* __restrict__ res,
                                              void* __restrict__ out,
                                              int M, int N, int K) {
  __shared__ __align__(16) u16 ls[4][2][256 * 32];  // [buf][A|B][r*32+c] = 128 KiB
  const int tid = threadIdx.x;
  const int lane = tid & 63, w = tid >> 6;  // 8 waves
  const int lane15 = lane & 15, khi = lane >> 4;
  const int wr = w >> 2, wcn = w & 3;       // 2 M-halves x 4 N-quarters

  // XCD-aware chunked swizzle (bijective: nwg % 8 == 0 for all our grids)
  const int gx = gridDim.x;
  const int nwg = gx * gridDim.y;
  const int orig = blockIdx.y * gx + blockIdx.x;
  const int wgid = (orig & 7) * (nwg >> 3) + (orig >> 3);
  const int bx = wgid % gx, by = wgid / gx;
  const long rowB = (long)by * 256, colB = (long)bx * 256;

  // staging geometry: per tensor per tile = 2 gload calls; call j, lane covers
  // r = j*128 + w*16 + (lane>>2), byte col = (lane&3)*16 (linear dest),
  // source col pre-swizzled by sw(r).
  const int sr = w * 16 + (lane >> 2);
  const int scb = (lane & 3) * 16;

  auto stageA = [&](int b, int kt) {
#pragma unroll
    for (int j = 0; j < 2; ++j) {
      int r = j * 128 + sr;
      int sw = ((r >> 1) & 3) << 4;
      gload16(A + (rowB + r) * (long)K + kt * 32 + ((scb ^ sw) >> 1),
              &ls[b][0][j * 4096 + w * 512]);
    }
  };
  auto stageB = [&](int b, int kt) {
#pragma unroll
    for (int j = 0; j < 2; ++j) {
      int r = j * 128 + sr;
      int sw = ((r >> 1) & 3) << 4;
      gload16(Bt + (colB + r) * (long)K + kt * 32 + ((scb ^ sw) >> 1),
              &ls[b][1][j * 4096 + w * 512]);
    }
  };
  auto rdA = [&](int b, int m) -> short8 {
    int r = wr * 128 + m * 16 + lane15;
    int c8 = (khi ^ ((r >> 1) & 3)) * 8;
    return *(const short8*)&ls[b][0][r * 32 + c8];
  };
  auto rdB = [&](int b, int n) -> short8 {
    int r = wcn * 64 + n * 16 + lane15;
    int c8 = (khi ^ ((r >> 1) & 3)) * 8;
    return *(const short8*)&ls[b][1][r * 32 + c8];
  };

  floatx4 acc[8][4];
#pragma unroll
  for (int m = 0; m < 8; ++m)
#pragma unroll
    for (int n = 0; n < 4; ++n) acc[m][n] = floatx4{0.f, 0.f, 0.f, 0.f};

  // prologue: stage tiles 0 and 1 (8 calls/wave-group); counted drain of tile 0
  stageA(0, 0); stageB(0, 0);
  stageA(1, 1); stageB(1, 1);
  asm volatile("s_waitcnt vmcnt(4)" ::: "memory");
  __builtin_amdgcn_s_barrier();

  const int NT = K >> 5;
  for (int t = 0; t < NT; ++t) {
    const int b = t & 3;
    // ---- phase 0: read B(all) + A(m0-3), stage A(t+2), MFMA upper half ----
    short8 bfr[4], afr[4];
#pragma unroll
    for (int n = 0; n < 4; ++n) bfr[n] = rdB(b, n);
#pragma unroll
    for (int m = 0; m < 4; ++m) afr[m] = rdA(b, m);
    if (t + 2 < NT) stageA((t + 2) & 3, t + 2);
    __builtin_amdgcn_sched_barrier(0);
    __builtin_amdgcn_s_barrier();
    __builtin_amdgcn_s_setprio(1);
#pragma unroll
    for (int n = 0; n < 4; ++n)
#pragma unroll
      for (int m = 0; m < 4; ++m)
        acc[m][n] = __builtin_amdgcn_mfma_f32_16x16x32_bf16(afr[m], bfr[n], acc[m][n], 0, 0, 0);
    __builtin_amdgcn_s_setprio(0);
    __builtin_amdgcn_s_barrier();
    // ---- phase 1: read A(m4-7), stage B(t+2), MFMA lower half ----
#pragma unroll
    for (int m = 0; m < 4; ++m) afr[m] = rdA(b, m + 4);
    if (t + 2 < NT) stageB((t + 2) & 3, t + 2);
    __builtin_amdgcn_sched_barrier(0);
    __builtin_amdgcn_s_barrier();
    __builtin_amdgcn_s_setprio(1);
#pragma unroll
    for (int n = 0; n < 4; ++n)
#pragma unroll
      for (int m = 0; m < 4; ++m)
        acc[m + 4][n] = __builtin_amdgcn_mfma_f32_16x16x32_bf16(afr[m], bfr[n], acc[m + 4][n], 0, 0, 0);
    __builtin_amdgcn_s_setprio(0);
    // counted drain: tile t+1's 4 calls are the oldest; keep t+2's in flight
    if (t + 2 < NT) {
      asm volatile("s_waitcnt vmcnt(4)" ::: "memory");
    } else if (t + 1 < NT) {
      asm volatile("s_waitcnt vmcnt(0)" ::: "memory");
    }
    __builtin_amdgcn_s_barrier();
  }

  const long r0 = rowB + wr * 128;
  const long c0 = colB + wcn * 64;
#pragma unroll
  for (int m = 0; m < 8; ++m) {
#pragma unroll
    for (int n = 0; n < 4; ++n) {
      long col = c0 + n * 16 + lane15;
      float bv = bias[col];
#pragma unroll
      for (int jj = 0; jj < 4; ++jj) {
        long row = r0 + m * 16 + khi * 4 + jj;
        float v = acc[m][n][jj] + bv;
        if (EPI == 1) v = 0.5f * v * (1.f + erff(v * 0.70710678118f));
        if (EPI == 2 || EPI == 3) v += bf2f(res[row * N + col]);
        if (EPI == 3) {
          ((float*)out)[row * N + col] = v;
        } else {
          ((u16*)out)[row * N + col] = f2bf(v);
        }
      }
    }
  }
}

// ---------- fused causal attention, one workgroup per (b,a,h) ----------
// qkv: [32768, 1536] bf16 (q|k|v each 512 cols, head h at h*64). y: [32768,512] bf16
__global__ __launch_bounds__(256) void attn_k(const u16* __restrict__ qkv,
                                              u16* __restrict__ y) {
  union U {
    struct { u16 q[128 * 64]; u16 k[128 * 64]; } qk;
    u16 p[128 * 128];
  };
  __shared__ __align__(16) U u;
  __shared__ __align__(16) u16 vt[64 * 128];

  const int tid = threadIdx.x;
  const int lane = tid & 63, wid = tid >> 6;
  const int lane15 = lane & 15, khi = lane >> 4;
  const int h = blockIdx.x & 7;
  const long R0 = (long)(blockIdx.x >> 3) * 128;
  const u16* base = qkv + R0 * 1536 + h * 64;

#pragma unroll
  for (int it = 0; it < 4; ++it) {
    int c = it * 256 + tid;
    int r = c >> 3, ch = c & 7;
    const u16* gq = base + (long)r * 1536 + ch * 8;
    uint4 dq = *(const uint4*)gq;
    uint4 dk = *(const uint4*)(gq + 512);
    uint4 dv = *(const uint4*)(gq + 1024);
    int qi = (r * 64 + ch * 8) ^ ((r & 7) << 3);
    *(uint4*)&u.qk.q[qi] = dq;
    *(uint4*)&u.qk.k[qi] = dk;
    u16 tmp[8];
    *(uint4*)tmp = dv;
#pragma unroll
    for (int i = 0; i < 8; ++i) {
      int d = ch * 8 + i;
      vt[(d * 128 + r) ^ ((d & 7) << 3)] = tmp[i];
    }
  }
  __syncthreads();

  const int r0 = wid * 32;
  floatx4 sc[2][8];
#pragma unroll
  for (int mt = 0; mt < 2; ++mt)
#pragma unroll
    for (int c = 0; c < 8; ++c) sc[mt][c] = floatx4{0.f, 0.f, 0.f, 0.f};

#pragma unroll
  for (int kk = 0; kk < 2; ++kk) {
    short8 aq[2];
#pragma unroll
    for (int mt = 0; mt < 2; ++mt) {
      int rr = r0 + mt * 16 + lane15;
      aq[mt] = *(const short8*)&u.qk.q[(rr * 64 + kk * 32 + khi * 8) ^ ((rr & 7) << 3)];
    }
#pragma unroll
    for (int c = 0; c < 8; ++c) {
      int rk = c * 16 + lane15;
      short8 bk = *(const short8*)&u.qk.k[(rk * 64 + kk * 32 + khi * 8) ^ ((rk & 7) << 3)];
#pragma unroll
      for (int mt = 0; mt < 2; ++mt)
        sc[mt][c] = __builtin_amdgcn_mfma_f32_16x16x32_bf16(aq[mt], bk, sc[mt][c], 0, 0, 0);
    }
  }
  __syncthreads();

#pragma unroll
  for (int mt = 0; mt < 2; ++mt) {
#pragma unroll
    for (int jj = 0; jj < 4; ++jj) {
      int t = r0 + mt * 16 + khi * 4 + jj;
      float vals[8];
      float mx = -1e30f;
#pragma unroll
      for (int c = 0; c < 8; ++c) {
        int s = c * 16 + lane15;
        float v = sc[mt][c][jj] * 0.125f;
        vals[c] = (s <= t) ? v : -1e30f;
        mx = fmaxf(mx, vals[c]);
      }
#pragma unroll
      for (int off = 1; off < 16; off <<= 1) mx = fmaxf(mx, __shfl_xor(mx, off, 64));
      float sum = 0.f;
#pragma unroll
      for (int c = 0; c < 8; ++c) {
        float p = __expf(vals[c] - mx);
        vals[c] = p;
        sum += p;
      }
#pragma unroll
      for (int off = 1; off < 16; off <<= 1) sum += __shfl_xor(sum, off, 64);
      float inv = 1.f / sum;
#pragma unroll
      for (int c = 0; c < 8; ++c) {
        int s = c * 16 + lane15;
        u.p[(t * 128 + s) ^ ((t & 7) << 3)] = f2bf(vals[c] * inv);
      }
    }
  }
  __syncthreads();

  floatx4 ya[2][4];
#pragma unroll
  for (int mt = 0; mt < 2; ++mt)
#pragma unroll
    for (int n = 0; n < 4; ++n) ya[mt][n] = floatx4{0.f, 0.f, 0.f, 0.f};

#pragma unroll
  for (int kk = 0; kk < 4; ++kk) {
    short8 ap[2];
#pragma unroll
    for (int mt = 0; mt < 2; ++mt) {
      int rr = r0 + mt * 16 + lane15;
      ap[mt] = *(const short8*)&u.p[(rr * 128 + kk * 32 + khi * 8) ^ ((rr & 7) << 3)];
    }
#pragma unroll
    for (int n = 0; n < 4; ++n) {
      int d = n * 16 + lane15;
      short8 bv = *(const short8*)&vt[(d * 128 + kk * 32 + khi * 8) ^ ((d & 7) << 3)];
#pragma unroll
      for (int mt = 0; mt < 2; ++mt)
        ya[mt][n] = __builtin_amdgcn_mfma_f32_16x16x32_bf16(ap[mt], bv, ya[mt][n], 0, 0, 0);
    }
  }

  u16* yb = y + R0 * 512 + h * 64;
#pragma unroll
  for (int mt = 0; mt < 2; ++mt)
#pragma unroll
    for (int n = 0; n < 4; ++n)
#pragma unroll
      for (int jj = 0; jj < 4; ++jj) {
        int t = r0 + mt * 16 + khi * 4 + jj;
        int d = n * 16 + lane15;
        yb[(long)t * 512 + d] = f2bf(ya[mt][n][jj]);
      }
}

// ---------- launch ----------
// ws layout (liveness-packed, peak 168 MiB) — unchanged from R7/R8.
extern "C" void kernel_launch(void* const* d_in, const int* in_sizes, int n_in,
                              void* d_out, int out_size, void* d_ws, size_t ws_size,
                              hipStream_t stream) {
  const float* x      = (const float*)d_in[0];
  const float* ln1_g  = (const float*)d_in[1];
  const float* ln1_b  = (const float*)d_in[2];
  const float* W_qkv  = (const float*)d_in[3];
  const float* b_qkv  = (const float*)d_in[4];
  const float* W_proj = (const float*)d_in[5];
  const float* b_proj = (const float*)d_in[6];
  const float* ln2_g  = (const float*)d_in[7];
  const float* ln2_b  = (const float*)d_in[8];
  const float* W_fc   = (const float*)d_in[9];
  const float* b_fc   = (const float*)d_in[10];
  const float* W_out  = (const float*)d_in[11];
  const float* b_out  = (const float*)d_in[12];

  const size_t MiB = 1024 * 1024;
  char* ws = (char*)d_ws;
  u16* wq   = (u16*)(ws + 0);
  u16* wp   = (u16*)(ws + 1536 * 512 * 2);
  u16* wf   = (u16*)(ws + 2 * MiB);
  u16* wo   = (u16*)(ws + 4 * MiB);
  u16* xnB  = (u16*)(ws + 8 * MiB);
  u16* qkvB = (u16*)(ws + 40 * MiB);
  u16* yB   = (u16*)(ws + 136 * MiB);
  u16* x2B  = (u16*)(ws + 40 * MiB);
  u16* xn2B = (u16*)(ws + 8 * MiB);
  u16* hB   = (u16*)(ws + 40 * MiB);

  const int M = 32768;

  tcast_k<<<dim3(1536 / 32, 512 / 32), dim3(32, 8), 0, stream>>>(W_qkv, wq, 512, 1536);
  tcast_k<<<dim3(512 / 32, 512 / 32), dim3(32, 8), 0, stream>>>(W_proj, wp, 512, 512);
  tcast_k<<<dim3(2048 / 32, 512 / 32), dim3(32, 8), 0, stream>>>(W_fc, wf, 512, 2048);
  tcast_k<<<dim3(512 / 32, 2048 / 32), dim3(32, 8), 0, stream>>>(W_out, wo, 2048, 512);

  ln_k<float><<<M / 4, 256, 0, stream>>>(x, ln1_g, ln1_b, xnB);
  // QKV: M x 1536, K=512
  gemm_k<0><<<dim3(1536 / 256, M / 256), 512, 0, stream>>>(xnB, wq, b_qkv, nullptr,
                                                           qkvB, M, 1536, 512);
  attn_k<<<2048, 256, 0, stream>>>(qkvB, yB);
  // proj + residual(xn): M x 512, K=512
  gemm_k<2><<<dim3(512 / 256, M / 256), 512, 0, stream>>>(yB, wp, b_proj, xnB,
                                                          x2B, M, 512, 512);
  ln_k<u16><<<M / 4, 256, 0, stream>>>(x2B, ln2_g, ln2_b, xn2B);
  // FC + gelu: M x 2048, K=512
  gemm_k<1><<<dim3(2048 / 256, M / 256), 512, 0, stream>>>(xn2B, wf, b_fc, nullptr,
                                                           hB, M, 2048, 512);
  // OUT + residual(xn2): M x 512, K=2048
  gemm_k<3><<<dim3(512 / 256, M / 256), 512, 0, stream>>>(hB, wo, b_out, xn2B,
                                                          (float*)d_out, M, 512, 2048);
}

// Round 12
// 446.553 us; speedup vs baseline: 1.1925x; 1.0652x over previous
//
#include <hip/hip_runtime.h>
#include <math.h>

#define DEV static __device__ __forceinline__

typedef unsigned short u16;
typedef __attribute__((ext_vector_type(8))) short short8;
typedef __attribute__((ext_vector_type(4))) float floatx4;

// ---------- helpers ----------
DEV u16 f2bf(float f) {
  unsigned u = __float_as_uint(f);
  unsigned r = u + 0x7FFFu + ((u >> 16) & 1u);
  return (u16)(r >> 16);
}
DEV float bf2f(u16 v) { return __uint_as_float(((unsigned)v) << 16); }

typedef __attribute__((address_space(1))) void gvoid;
typedef __attribute__((address_space(3))) void lvoid;

DEV void gload16(const u16* g, u16* l) {
  // async global->LDS, 16B per lane; LDS dest = wave-uniform base + lane*16
  __builtin_amdgcn_global_load_lds((gvoid*)g, (lvoid*)l, 16, 0, 0);
}

// ---------- weight convert + transpose: out[n*K+k] = bf16(in[k*N+n]) ----------
__global__ __launch_bounds__(256) void tcast_k(const float* __restrict__ in,
                                               u16* __restrict__ out, int K, int N) {
  __shared__ float t[32][33];
  int nb = blockIdx.x * 32, kb = blockIdx.y * 32;
  int tx = threadIdx.x, ty = threadIdx.y;
#pragma unroll
  for (int r = 0; r < 32; r += 8)
    t[r + ty][tx] = in[(long)(kb + r + ty) * N + nb + tx];
  __syncthreads();
#pragma unroll
  for (int r = 0; r < 32; r += 8)
    out[(long)(nb + r + ty) * K + kb + tx] = f2bf(t[tx][r + ty]);
}

// ---------- layernorm: wave per row (D=512), bf16 out ----------
template <typename TI>
__global__ __launch_bounds__(256) void ln_k(const TI* __restrict__ x,
                                            const float* __restrict__ g,
                                            const float* __restrict__ b,
                                            u16* __restrict__ xb) {
  const int lane = threadIdx.x & 63, wid = threadIdx.x >> 6;
  const long row = (long)blockIdx.x * 4 + wid;
  float vv[8];
  if constexpr (sizeof(TI) == 4) {
    const float4* xr = (const float4*)((const float*)x + row * 512);
    float4 v0 = xr[lane * 2], v1 = xr[lane * 2 + 1];
    vv[0] = v0.x; vv[1] = v0.y; vv[2] = v0.z; vv[3] = v0.w;
    vv[4] = v1.x; vv[5] = v1.y; vv[6] = v1.z; vv[7] = v1.w;
  } else {
    short8 v = *(const short8*)((const u16*)x + row * 512 + lane * 8);
#pragma unroll
    for (int i = 0; i < 8; ++i) vv[i] = bf2f((u16)v[i]);
  }
  float s = 0.f, q = 0.f;
#pragma unroll
  for (int i = 0; i < 8; ++i) { s += vv[i]; q += vv[i] * vv[i]; }
#pragma unroll
  for (int off = 1; off < 64; off <<= 1) {
    s += __shfl_xor(s, off, 64);
    q += __shfl_xor(q, off, 64);
  }
  float mean = s * (1.f / 512.f);
  float var = q * (1.f / 512.f) - mean * mean;
  float rs = rsqrtf(var + 1e-5f);
  const float4* gp = (const float4*)g;
  const float4* bp = (const float4*)b;
  float4 g0 = gp[lane * 2], g1 = gp[lane * 2 + 1];
  float4 b0 = bp[lane * 2], b1 = bp[lane * 2 + 1];
  float gg[8] = {g0.x, g0.y, g0.z, g0.w, g1.x, g1.y, g1.z, g1.w};
  float bb[8] = {b0.x, b0.y, b0.z, b0.w, b1.x, b1.y, b1.z, b1.w};
  short8 ov;
#pragma unroll
  for (int i = 0; i < 8; ++i)
    ov[i] = (short)f2bf((vv[i] - mean) * rs * gg[i] + bb[i]);
  *(short8*)&xb[row * 512 + lane * 8] = ov;
}

// ---------- GEMM 128x128, 4 waves, BK=64, single-buffer, conflict-free LDS ----------
// C[M,N] = A[M,K](bf16) * Bt[N,K]^T(bf16) + bias, epilogue as before.
// LDS row = 64 u16 = 8 x 16B granules; slot s holds logical granule s^(r&7)
// (write-side source pre-swizzle == read-side XOR; linear gload_lds dest).
// __launch_bounds__(256,4): 4 blocks/CU (32KB LDS) -> cross-block latency hiding.
template <int EPI>
__global__ __launch_bounds__(256, 4) void gemm_k(const u16* __restrict__ A,
                                                 const u16* __restrict__ Bt,
                                                 const float* __restrict__ bias,
                                                 const u16* __restrict__ res,
                                                 void* __restrict__ out,
                                                 int M, int N, int K) {
  __shared__ __align__(16) u16 lA[128 * 64];
  __shared__ __align__(16) u16 lB[128 * 64];
  const int tid = threadIdx.x;
  const int lane = tid & 63, w = tid >> 6;
  const int lane15 = lane & 15, khi = lane >> 4;
  const int wr = w >> 1, wc = w & 1;

  // XCD-aware chunked swizzle (bijective: nwg % 8 == 0 for all our grids)
  const int gx = gridDim.x;
  const int nwg = gx * gridDim.y;
  const int orig = blockIdx.y * gx + blockIdx.x;
  const int wgid = (orig & 7) * (nwg >> 3) + (orig >> 3);
  const int bx = wgid % gx, by = wgid / gx;
  const long rowB = (long)by * 128, colB = (long)bx * 128;

  // staging: per tensor per tile = 4 gloads/wave; call j covers rows
  // w*32+j*8 .. +7. lane l -> row += (l>>3), slot l&7 <- logical granule
  // (l&7)^(l>>3) (since r&7 == l>>3).
  const int srow = w * 32 + (lane >> 3);
  const int sswz = ((lane & 7) ^ (lane >> 3)) * 8;  // u16 offset within row
  const u16* gA0 = A + (rowB + srow) * (long)K + sswz;
  const u16* gB0 = Bt + (colB + srow) * (long)K + sswz;
  const long j8K = 8 * (long)K;

  // ds-read slot xor: logical granule kk*4+khi, r&7 == lane15&7
  const int rx = lane15 & 7;
  const int s0 = (khi ^ rx) * 8;        // kk=0
  const int s1 = ((4 + khi) ^ rx) * 8;  // kk=1

  floatx4 acc[4][4];
#pragma unroll
  for (int m = 0; m < 4; ++m)
#pragma unroll
    for (int n = 0; n < 4; ++n) acc[m][n] = floatx4{0.f, 0.f, 0.f, 0.f};

  const int NT = K >> 6;
  for (int t = 0; t < NT; ++t) {
    const long kt = (long)t << 6;
    __syncthreads();  // previous tile's readers done
#pragma unroll
    for (int j = 0; j < 4; ++j) {
      gload16(gA0 + j * j8K + kt, &lA[(w * 4 + j) * 512]);
      gload16(gB0 + j * j8K + kt, &lB[(w * 4 + j) * 512]);
    }
    asm volatile("s_waitcnt vmcnt(0)" ::: "memory");
    __syncthreads();

#pragma unroll
    for (int kk = 0; kk < 2; ++kk) {
      const int sk = kk ? s1 : s0;
      short8 af[4];
#pragma unroll
      for (int m = 0; m < 4; ++m)
        af[m] = *(const short8*)&lA[(wr * 64 + m * 16 + lane15) * 64 + sk];
#pragma unroll
      for (int n = 0; n < 4; ++n) {
        short8 bfg = *(const short8*)&lB[(wc * 64 + n * 16 + lane15) * 64 + sk];
#pragma unroll
        for (int m = 0; m < 4; ++m)
          acc[m][n] = __builtin_amdgcn_mfma_f32_16x16x32_bf16(af[m], bfg, acc[m][n], 0, 0, 0);
      }
    }
  }

  const long r0 = rowB + wr * 64;
  const long c0 = colB + wc * 64;
#pragma unroll
  for (int m = 0; m < 4; ++m) {
#pragma unroll
    for (int n = 0; n < 4; ++n) {
      long col = c0 + n * 16 + lane15;
      float bv = bias[col];
#pragma unroll
      for (int jj = 0; jj < 4; ++jj) {
        long row = r0 + m * 16 + khi * 4 + jj;
        float v = acc[m][n][jj] + bv;
        if (EPI == 1) v = 0.5f * v * (1.f + erff(v * 0.70710678118f));
        if (EPI == 2 || EPI == 3) v += bf2f(res[row * N + col]);
        if (EPI == 3) {
          ((float*)out)[row * N + col] = v;
        } else {
          ((u16*)out)[row * N + col] = f2bf(v);
        }
      }
    }
  }
}

// ---------- fused causal attention, one workgroup per (b,a,h) ----------
// qkv: [32768, 1536] bf16 (q|k|v each 512 cols, head h at h*64). y: [32768,512] bf16
__global__ __launch_bounds__(256) void attn_k(const u16* __restrict__ qkv,
                                              u16* __restrict__ y) {
  union U {
    struct { u16 q[128 * 64]; u16 k[128 * 64]; } qk;
    u16 p[128 * 128];
  };
  __shared__ __align__(16) U u;
  __shared__ __align__(16) u16 vt[64 * 128];

  const int tid = threadIdx.x;
  const int lane = tid & 63, wid = tid >> 6;
  const int lane15 = lane & 15, khi = lane >> 4;
  const int h = blockIdx.x & 7;
  const long R0 = (long)(blockIdx.x >> 3) * 128;
  const u16* base = qkv + R0 * 1536 + h * 64;

#pragma unroll
  for (int it = 0; it < 4; ++it) {
    int c = it * 256 + tid;
    int r = c >> 3, ch = c & 7;
    const u16* gq = base + (long)r * 1536 + ch * 8;
    uint4 dq = *(const uint4*)gq;
    uint4 dk = *(const uint4*)(gq + 512);
    uint4 dv = *(const uint4*)(gq + 1024);
    int qi = (r * 64 + ch * 8) ^ ((r & 7) << 3);
    *(uint4*)&u.qk.q[qi] = dq;
    *(uint4*)&u.qk.k[qi] = dk;
    u16 tmp[8];
    *(uint4*)tmp = dv;
#pragma unroll
    for (int i = 0; i < 8; ++i) {
      int d = ch * 8 + i;
      vt[(d * 128 + r) ^ ((d & 7) << 3)] = tmp[i];
    }
  }
  __syncthreads();

  const int r0 = wid * 32;
  floatx4 sc[2][8];
#pragma unroll
  for (int mt = 0; mt < 2; ++mt)
#pragma unroll
    for (int c = 0; c < 8; ++c) sc[mt][c] = floatx4{0.f, 0.f, 0.f, 0.f};

#pragma unroll
  for (int kk = 0; kk < 2; ++kk) {
    short8 aq[2];
#pragma unroll
    for (int mt = 0; mt < 2; ++mt) {
      int rr = r0 + mt * 16 + lane15;
      aq[mt] = *(const short8*)&u.qk.q[(rr * 64 + kk * 32 + khi * 8) ^ ((rr & 7) << 3)];
    }
#pragma unroll
    for (int c = 0; c < 8; ++c) {
      int rk = c * 16 + lane15;
      short8 bk = *(const short8*)&u.qk.k[(rk * 64 + kk * 32 + khi * 8) ^ ((rk & 7) << 3)];
#pragma unroll
      for (int mt = 0; mt < 2; ++mt)
        sc[mt][c] = __builtin_amdgcn_mfma_f32_16x16x32_bf16(aq[mt], bk, sc[mt][c], 0, 0, 0);
    }
  }
  __syncthreads();

#pragma unroll
  for (int mt = 0; mt < 2; ++mt) {
#pragma unroll
    for (int jj = 0; jj < 4; ++jj) {
      int t = r0 + mt * 16 + khi * 4 + jj;
      float vals[8];
      float mx = -1e30f;
#pragma unroll
      for (int c = 0; c < 8; ++c) {
        int s = c * 16 + lane15;
        float v = sc[mt][c][jj] * 0.125f;
        vals[c] = (s <= t) ? v : -1e30f;
        mx = fmaxf(mx, vals[c]);
      }
#pragma unroll
      for (int off = 1; off < 16; off <<= 1) mx = fmaxf(mx, __shfl_xor(mx, off, 64));
      float sum = 0.f;
#pragma unroll
      for (int c = 0; c < 8; ++c) {
        float p = __expf(vals[c] - mx);
        vals[c] = p;
        sum += p;
      }
#pragma unroll
      for (int off = 1; off < 16; off <<= 1) sum += __shfl_xor(sum, off, 64);
      float inv = 1.f / sum;
#pragma unroll
      for (int c = 0; c < 8; ++c) {
        int s = c * 16 + lane15;
        u.p[(t * 128 + s) ^ ((t & 7) << 3)] = f2bf(vals[c] * inv);
      }
    }
  }
  __syncthreads();

  floatx4 ya[2][4];
#pragma unroll
  for (int mt = 0; mt < 2; ++mt)
#pragma unroll
    for (int n = 0; n < 4; ++n) ya[mt][n] = floatx4{0.f, 0.f, 0.f, 0.f};

#pragma unroll
  for (int kk = 0; kk < 4; ++kk) {
    short8 ap[2];
#pragma unroll
    for (int mt = 0; mt < 2; ++mt) {
      int rr = r0 + mt * 16 + lane15;
      ap[mt] = *(const short8*)&u.p[(rr * 128 + kk * 32 + khi * 8) ^ ((rr & 7) << 3)];
    }
#pragma unroll
    for (int n = 0; n < 4; ++n) {
      int d = n * 16 + lane15;
      short8 bv = *(const short8*)&vt[(d * 128 + kk * 32 + khi * 8) ^ ((d & 7) << 3)];
#pragma unroll
      for (int mt = 0; mt < 2; ++mt)
        ya[mt][n] = __builtin_amdgcn_mfma_f32_16x16x32_bf16(ap[mt], bv, ya[mt][n], 0, 0, 0);
    }
  }

  u16* yb = y + R0 * 512 + h * 64;
#pragma unroll
  for (int mt = 0; mt < 2; ++mt)
#pragma unroll
    for (int n = 0; n < 4; ++n)
#pragma unroll
      for (int jj = 0; jj < 4; ++jj) {
        int t = r0 + mt * 16 + khi * 4 + jj;
        int d = n * 16 + lane15;
        yb[(long)t * 512 + d] = f2bf(ya[mt][n][jj]);
      }
}

// ---------- launch ----------
// ws layout (liveness-packed, peak 168 MiB) — unchanged.
extern "C" void kernel_launch(void* const* d_in, const int* in_sizes, int n_in,
                              void* d_out, int out_size, void* d_ws, size_t ws_size,
                              hipStream_t stream) {
  const float* x      = (const float*)d_in[0];
  const float* ln1_g  = (const float*)d_in[1];
  const float* ln1_b  = (const float*)d_in[2];
  const float* W_qkv  = (const float*)d_in[3];
  const float* b_qkv  = (const float*)d_in[4];
  const float* W_proj = (const float*)d_in[5];
  const float* b_proj = (const float*)d_in[6];
  const float* ln2_g  = (const float*)d_in[7];
  const float* ln2_b  = (const float*)d_in[8];
  const float* W_fc   = (const float*)d_in[9];
  const float* b_fc   = (const float*)d_in[10];
  const float* W_out  = (const float*)d_in[11];
  const float* b_out  = (const float*)d_in[12];

  const size_t MiB = 1024 * 1024;
  char* ws = (char*)d_ws;
  u16* wq   = (u16*)(ws + 0);
  u16* wp   = (u16*)(ws + 1536 * 512 * 2);
  u16* wf   = (u16*)(ws + 2 * MiB);
  u16* wo   = (u16*)(ws + 4 * MiB);
  u16* xnB  = (u16*)(ws + 8 * MiB);
  u16* qkvB = (u16*)(ws + 40 * MiB);
  u16* yB   = (u16*)(ws + 136 * MiB);
  u16* x2B  = (u16*)(ws + 40 * MiB);
  u16* xn2B = (u16*)(ws + 8 * MiB);
  u16* hB   = (u16*)(ws + 40 * MiB);

  const int M = 32768;

  tcast_k<<<dim3(1536 / 32, 512 / 32), dim3(32, 8), 0, stream>>>(W_qkv, wq, 512, 1536);
  tcast_k<<<dim3(512 / 32, 512 / 32), dim3(32, 8), 0, stream>>>(W_proj, wp, 512, 512);
  tcast_k<<<dim3(2048 / 32, 512 / 32), dim3(32, 8), 0, stream>>>(W_fc, wf, 512, 2048);
  tcast_k<<<dim3(512 / 32, 2048 / 32), dim3(32, 8), 0, stream>>>(W_out, wo, 2048, 512);

  ln_k<float><<<M / 4, 256, 0, stream>>>(x, ln1_g, ln1_b, xnB);
  // QKV: M x 1536, K=512
  gemm_k<0><<<dim3(1536 / 128, M / 128), 256, 0, stream>>>(xnB, wq, b_qkv, nullptr,
                                                           qkvB, M, 1536, 512);
  attn_k<<<2048, 256, 0, stream>>>(qkvB, yB);
  // proj + residual(xn): M x 512, K=512
  gemm_k<2><<<dim3(512 / 128, M / 128), 256, 0, stream>>>(yB, wp, b_proj, xnB,
                                                          x2B, M, 512, 512);
  ln_k<u16><<<M / 4, 256, 0, stream>>>(x2B, ln2_g, ln2_b, xn2B);
  // FC + gelu: M x 2048, K=512
  gemm_k<1><<<dim3(2048 / 128, M / 128), 256, 0, stream>>>(xn2B, wf, b_fc, nullptr,
                                                           hB, M, 2048, 512);
  // OUT + residual(xn2): M x 512, K=2048
  gemm_k<3><<<dim3(512 / 128, M / 128), 256, 0, stream>>>(hB, wo, b_out, xn2B,
                                                          (float*)d_out, M, 512, 2048);
}